// Round 8
// baseline (178.941 us; speedup 1.0000x reference)
//
#include <hip/hip_runtime.h>

#define Lq 512
#define Bn 1024
#define Tq 48

typedef float f32x4 __attribute__((ext_vector_type(4)));

// One recursion step. Broadcast of p via LDS same-address reads (DS pipe,
// conflict-free, co-issues with VALU). EV is a RAW emission value loaded
// >= 8 steps ago (no vmcnt stall); exp(EV) hoisted above the DS round-trip.
// P = (sum_i P[i]*W[i][j]) * exp(EV)  if MV else P
#define STEP(EV, MV) do {                                                     \
    float exv_ = __expf(EV);          /* off the DS critical path */          \
    sh[j] = p;                        /* ds_write_b32; in-order DS pipe */    \
    const f32x4* shp_ = (const f32x4*)sh;                                     \
    float a0_ = 0.f, a1_ = 0.f, a2_ = 0.f, a3_ = 0.f;                         \
    {                                                                         \
        f32x4 r0_ = shp_[0], r1_ = shp_[1], r2_ = shp_[2], r3_ = shp_[3];     \
        a0_=fmaf(r0_.x,w[0],a0_);  a1_=fmaf(r0_.y,w[1],a1_);                  \
        a2_=fmaf(r0_.z,w[2],a2_);  a3_=fmaf(r0_.w,w[3],a3_);                  \
        a0_=fmaf(r1_.x,w[4],a0_);  a1_=fmaf(r1_.y,w[5],a1_);                  \
        a2_=fmaf(r1_.z,w[6],a2_);  a3_=fmaf(r1_.w,w[7],a3_);                  \
        a0_=fmaf(r2_.x,w[8],a0_);  a1_=fmaf(r2_.y,w[9],a1_);                  \
        a2_=fmaf(r2_.z,w[10],a2_); a3_=fmaf(r2_.w,w[11],a3_);                 \
        a0_=fmaf(r3_.x,w[12],a0_); a1_=fmaf(r3_.y,w[13],a1_);                 \
        a2_=fmaf(r3_.z,w[14],a2_); a3_=fmaf(r3_.w,w[15],a3_);                 \
    }                                                                         \
    {                                                                         \
        f32x4 r4_ = shp_[4], r5_ = shp_[5], r6_ = shp_[6], r7_ = shp_[7];     \
        a0_=fmaf(r4_.x,w[16],a0_); a1_=fmaf(r4_.y,w[17],a1_);                 \
        a2_=fmaf(r4_.z,w[18],a2_); a3_=fmaf(r4_.w,w[19],a3_);                 \
        a0_=fmaf(r5_.x,w[20],a0_); a1_=fmaf(r5_.y,w[21],a1_);                 \
        a2_=fmaf(r5_.z,w[22],a2_); a3_=fmaf(r5_.w,w[23],a3_);                 \
        a0_=fmaf(r6_.x,w[24],a0_); a1_=fmaf(r6_.y,w[25],a1_);                 \
        a2_=fmaf(r6_.z,w[26],a2_); a3_=fmaf(r6_.w,w[27],a3_);                 \
        a0_=fmaf(r7_.x,w[28],a0_); a1_=fmaf(r7_.y,w[29],a1_);                 \
        a2_=fmaf(r7_.z,w[30],a2_); a3_=fmaf(r7_.w,w[31],a3_);                 \
    }                                                                         \
    {                                                                         \
        f32x4 r8_ = shp_[8], r9_ = shp_[9], r10_ = shp_[10], r11_ = shp_[11]; \
        a0_=fmaf(r8_.x,w[32],a0_);  a1_=fmaf(r8_.y,w[33],a1_);                \
        a2_=fmaf(r8_.z,w[34],a2_);  a3_=fmaf(r8_.w,w[35],a3_);                \
        a0_=fmaf(r9_.x,w[36],a0_);  a1_=fmaf(r9_.y,w[37],a1_);                \
        a2_=fmaf(r9_.z,w[38],a2_);  a3_=fmaf(r9_.w,w[39],a3_);                \
        a0_=fmaf(r10_.x,w[40],a0_); a1_=fmaf(r10_.y,w[41],a1_);               \
        a2_=fmaf(r10_.z,w[42],a2_); a3_=fmaf(r10_.w,w[43],a3_);               \
        a0_=fmaf(r11_.x,w[44],a0_); a1_=fmaf(r11_.y,w[45],a1_);               \
        a2_=fmaf(r11_.z,w[46],a2_); a3_=fmaf(r11_.w,w[47],a3_);               \
    }                                                                         \
    float s_ = (a0_ + a1_) + (a2_ + a3_);                                     \
    float pn_ = s_ * exv_;                                                    \
    p = (MV) ? pn_ : p;               /* branch-free masked update */         \
} while (0)

// refill slot D with step T's RAW e (exp happens at consume) and mask
#define LOAD_SLOT(D, T) do {                                                  \
    int t_ = (T); int v_ = (t_ <= Lq - 1); int tc_ = v_ ? t_ : (Lq - 1);      \
    e_##D = em[(size_t)tc_ * (Bn * Tq) + boff];                               \
    m_##D = v_ ? mask[tc_ * Bn + b] : 0;                                      \
} while (0)

// exact power-of-2 rescale from lane 0's exponent bits (every 4 steps)
#define RESCALE do {                                                          \
    int pb_ = __builtin_amdgcn_readlane(__float_as_int(p), 0);                \
    int k_ = (pb_ >> 23) - 126;                                               \
    p *= __int_as_float((127 - k_) << 23);                                    \
    c2 += k_;                                                                 \
} while (0)

// ---------------- Forward algorithm (log partition function) ----------------
// 1024 blocks x 64 threads = 1 wave/SIMD chip-wide. Lane j holds P[j] and
// W column j (48 VGPRs). Broadcast via LDS; emissions prefetched 8 steps
// ahead as raw values in named registers.
__global__ __launch_bounds__(64) void crf_forward(
    const float* __restrict__ em, const int* __restrict__ mask,
    const float* __restrict__ startT, const float* __restrict__ endT,
    const float* __restrict__ trans, float* __restrict__ out)
{
    const int j  = threadIdx.x;          // 0..63
    const int b  = blockIdx.x;           // wave-uniform
    const int jc = j < Tq ? j : Tq - 1;
    const bool act = j < Tq;
    const unsigned boff = (unsigned)b * Tq + (unsigned)jc;

    __shared__ float sh[64] __attribute__((aligned(16)));

    // W column j in 48 VGPRs; zero column for inactive lanes keeps their p=0
    float w[Tq];
#pragma unroll
    for (int i = 0; i < Tq; ++i) {
        float wv = __expf(trans[i * Tq + jc]);
        w[i] = act ? wv : 0.0f;
    }

    float p = act ? __expf(startT[jc] + em[boff]) : 0.0f;
    int c2 = 0;

    // 8 prefetch slots, named scalars (spill lesson, rounds 5-7)
    float e_0, e_1, e_2, e_3, e_4, e_5, e_6, e_7;
    int   m_0, m_1, m_2, m_3, m_4, m_5, m_6, m_7;
    LOAD_SLOT(0, 1); LOAD_SLOT(1, 2); LOAD_SLOT(2, 3); LOAD_SLOT(3, 4);
    LOAD_SLOT(4, 5); LOAD_SLOT(5, 6); LOAD_SLOT(6, 7); LOAD_SLOT(7, 8);

    // 64 chunks x 8 steps cover t = 1..512 (t=512 is a masked no-op)
    for (int c = 0; c < 64; ++c) {
        const int tb = 1 + 8 * c;
        STEP(e_0, m_0); LOAD_SLOT(0, tb + 8);
        STEP(e_1, m_1); LOAD_SLOT(1, tb + 9);
        STEP(e_2, m_2); LOAD_SLOT(2, tb + 10);
        STEP(e_3, m_3); LOAD_SLOT(3, tb + 11); RESCALE;
        STEP(e_4, m_4); LOAD_SLOT(4, tb + 12);
        STEP(e_5, m_5); LOAD_SLOT(5, tb + 13);
        STEP(e_6, m_6); LOAD_SLOT(6, tb + 14);
        STEP(e_7, m_7); LOAD_SLOT(7, tb + 15); RESCALE;
    }

    // log_z = ln(sum_j P[j]*exp(end[j])) + c2*ln2 ; accumulate -log_z
    float ez = act ? __expf(endT[jc]) : 0.0f;
    float z = p * ez;
#pragma unroll
    for (int off = 32; off >= 1; off >>= 1)
        z += __shfl_xor(z, off, 64);
    if (j == 0) {
        double lz = (double)__logf(z) + (double)c2 * 0.6931471805599453;
        atomicAdd(out, (float)(-lz));
    }
}

// ---------------- Numerator (gold-path score) ----------------
// Grid-stride over (t,b); block-reduce -> 1 atomic per block (512 total).
__global__ __launch_bounds__(256) void crf_llh(
    const float* __restrict__ em, const int* __restrict__ tags,
    const int* __restrict__ mask, const float* __restrict__ startT,
    const float* __restrict__ endT, const float* __restrict__ trans,
    float* __restrict__ out)
{
    float c = 0.0f;
    for (int id = blockIdx.x * blockDim.x + threadIdx.x; id < Lq * Bn;
         id += gridDim.x * blockDim.x) {
        int t  = id >> 10;          // / Bn (Bn = 1024)
        int bb = id & (Bn - 1);
        int tag = tags[id];
        int m_t = mask[id];
        if (t == 0) c += startT[tag];
        bool is_last;
        if (t < Lq - 1) {
            if (m_t) c += em[(size_t)id * Tq + tag];     // emis*mask[:-1]
            int tag1 = tags[id + Bn];
            int m1   = mask[id + Bn];
            if (m1) c += trans[tag * Tq + tag1];         // trans*mask[1:]
            is_last = (m_t != 0) && (m1 == 0);
        } else {
            is_last = (m_t != 0);
        }
        if (is_last) {
            c += endT[tag];
            int mL = mask[(Lq - 1) * Bn + bb];
            if (mL) c += em[((size_t)(Lq - 1) * Bn + bb) * Tq + tag];
        }
    }
#pragma unroll
    for (int off = 32; off >= 1; off >>= 1)
        c += __shfl_xor(c, off, 64);
    __shared__ float red[4];
    if ((threadIdx.x & 63) == 0) red[threadIdx.x >> 6] = c;
    __syncthreads();
    if (threadIdx.x == 0)
        atomicAdd(out, red[0] + red[1] + red[2] + red[3]);
}

extern "C" void kernel_launch(void* const* d_in, const int* in_sizes, int n_in,
                              void* d_out, int out_size, void* d_ws, size_t ws_size,
                              hipStream_t stream) {
    const float* em     = (const float*)d_in[0];
    const int*   tags   = (const int*)d_in[1];
    const int*   mask   = (const int*)d_in[2];
    const float* startT = (const float*)d_in[3];
    const float* endT   = (const float*)d_in[4];
    const float* trans  = (const float*)d_in[5];
    float* out = (float*)d_out;

    hipMemsetAsync(out, 0, sizeof(float), stream);
    crf_llh<<<512, 256, 0, stream>>>(em, tags, mask, startT, endT, trans, out);
    crf_forward<<<Bn, 64, 0, stream>>>(em, mask, startT, endT, trans, out);
}

// Round 9
// 150.589 us; speedup vs baseline: 1.1883x; 1.1883x over previous
//
#include <hip/hip_runtime.h>

#define Lq 512
#define Bn 1024
#define Tq 48

typedef float f32x4 __attribute__((ext_vector_type(4)));
typedef short s16x8 __attribute__((ext_vector_type(8)));

#define MFMA(a, b, c) __builtin_amdgcn_mfma_f32_16x16x32_bf16((a), (b), (c), 0, 0, 0)

__device__ __forceinline__ unsigned cvtpk(float lo, float hi) {
    unsigned r;
    asm("v_cvt_pk_bf16_f32 %0, %1, %2" : "=v"(r) : "v"(lo), "v"(hi));
    return r;
}
__device__ __forceinline__ short f2b(float x) {   // fp32 -> bf16 bits, RNE
    unsigned u = __float_as_uint(x);
    return (short)((u + 0x7fffu + ((u >> 16) & 1u)) >> 16);
}

// one forward step: C = W^T x P^T (6 MFMAs), apply exp(e)&mask, optional
// per-column rescale, then P^T -> LDS (bf16) -> next B fragments.
#define STEP(EA, EB, EC, MV, RS) do {                                         \
    f32x4 C0_ = MFMA(aw00, Bk0, Zf); C0_ = MFMA(aw01, Bk1, C0_);              \
    f32x4 C1_ = MFMA(aw10, Bk0, Zf); C1_ = MFMA(aw11, Bk1, C1_);              \
    f32x4 C2_ = MFMA(aw20, Bk0, Zf); C2_ = MFMA(aw21, Bk1, C2_);              \
    if ((MV) != 0) {                                                          \
        pn0[0]=C0_[0]*__expf((EA)[0]); pn0[1]=C0_[1]*__expf((EA)[1]);         \
        pn0[2]=C0_[2]*__expf((EA)[2]); pn0[3]=C0_[3]*__expf((EA)[3]);         \
        pn1[0]=C1_[0]*__expf((EB)[0]); pn1[1]=C1_[1]*__expf((EB)[1]);         \
        pn1[2]=C1_[2]*__expf((EB)[2]); pn1[3]=C1_[3]*__expf((EB)[3]);         \
        pn2[0]=C2_[0]*__expf((EC)[0]); pn2[1]=C2_[1]*__expf((EC)[1]);         \
        pn2[2]=C2_[2]*__expf((EC)[2]); pn2[3]=C2_[3]*__expf((EC)[3]);         \
    }                                                                         \
    if (RS) {                                                                 \
        float rep_ = __shfl(pn0[0], cidx, 64);      /* column c, state 0 */   \
        int k_ = ((__float_as_int(rep_) >> 23) & 0xff) - 126;                 \
        float scl_ = __int_as_float((127 - k_) << 23);                        \
        pn0[0]*=scl_; pn0[1]*=scl_; pn0[2]*=scl_; pn0[3]*=scl_;               \
        pn1[0]*=scl_; pn1[1]*=scl_; pn1[2]*=scl_; pn1[3]*=scl_;               \
        pn2[0]*=scl_; pn2[1]*=scl_; pn2[2]*=scl_; pn2[3]*=scl_;               \
        c2 += k_;                                                             \
    }                                                                         \
    *(uint2*)(ldsc + wr0) = make_uint2(cvtpk(pn0[0],pn0[1]), cvtpk(pn0[2],pn0[3])); \
    *(uint2*)(ldsc + wr1) = make_uint2(cvtpk(pn1[0],pn1[1]), cvtpk(pn1[2],pn1[3])); \
    *(uint2*)(ldsc + wr2) = make_uint2(cvtpk(pn2[0],pn2[1]), cvtpk(pn2[2],pn2[3])); \
    Bk0 = *(const s16x8*)(ldsc + rd0);                                        \
    Bk1 = *(const s16x8*)(ldsc + rd1);                                        \
} while (0)

// refill slot D with step T's raw emissions (3 x dwordx4) + mask
#define LOAD_SLOT(D, T) do {                                                  \
    int t_ = (T); int v_ = (t_ < Lq); int tc_ = v_ ? t_ : (Lq - 1);           \
    const float* ep_ = em + ((size_t)tc_ * Bn + bidx) * Tq;                   \
    ea_##D = *(const f32x4*)(ep_ + 4 * qidx);                                 \
    eb_##D = *(const f32x4*)(ep_ + 16 + 4 * qidx);                            \
    ec_##D = *(const f32x4*)(ep_ + 32 + 4 * qidx);                            \
    m_##D  = v_ ? mask[tc_ * Bn + bidx] : 0;                                  \
} while (0)

// ---------------- Forward algorithm via MFMA ----------------
// 64 blocks x 64 threads; each wave owns 16 batch columns.
// P^T (48x16) kept as bf16 in LDS; W^T as 6 preloaded A-fragments.
// Per step: 6 x mfma_f32_16x16x32_bf16 + elementwise exp/mask + LDS transpose.
__global__ __launch_bounds__(64) void crf_forward(
    const float* __restrict__ em, const int* __restrict__ mask,
    const float* __restrict__ startT, const float* __restrict__ endT,
    const float* __restrict__ trans, float* __restrict__ out)
{
    const int j = threadIdx.x;
    const int cidx = j & 15;          // batch column within wave
    const int qidx = j >> 4;          // k/row group
    const int b0 = blockIdx.x * 16;
    const int bidx = b0 + cidx;

    __shared__ float shf[2304];       // prologue: raw trans; then P^T region
    char* ldsc = (char*)shf;

    // stage trans coalesced, then build W^T A-fragments:
    // A[n][kb] lane(q,c) elem i = Wexp[32kb+8q+i][16n+c] (0 beyond 48)
    for (int i = j; i < Tq * Tq; i += 64) shf[i] = trans[i];
    __syncthreads();
    s16x8 aw00, aw01, aw10, aw11, aw20, aw21;
#pragma unroll
    for (int i = 0; i < 8; ++i) {
        int so0 = qidx * 8 + i;              // kb0: 0..31
        int so1 = 32 + qidx * 8 + i;         // kb1: 32..63 (pad >=48)
        aw00[i] = f2b(__expf(shf[so0 * Tq + cidx]));
        aw10[i] = f2b(__expf(shf[so0 * Tq + 16 + cidx]));
        aw20[i] = f2b(__expf(shf[so0 * Tq + 32 + cidx]));
        float w01 = so1 < Tq ? __expf(shf[so1 * Tq + cidx]) : 0.f;
        float w11 = so1 < Tq ? __expf(shf[so1 * Tq + 16 + cidx]) : 0.f;
        float w21 = so1 < Tq ? __expf(shf[so1 * Tq + 32 + cidx]) : 0.f;
        aw01[i] = f2b(w01); aw11[i] = f2b(w11); aw21[i] = f2b(w21);
    }
    __syncthreads();

    // zero pad regions of the P^T store (states 48..55 per row + zero block)
    if (j < 16) *(uint4*)(ldsc + j * 112 + 96) = make_uint4(0, 0, 0, 0);
    if (j == 16) *(uint4*)(ldsc + 1792) = make_uint4(0, 0, 0, 0);

    // P_0 in C-layout: pn_n[i] = exp(start[s] + em[0][b][s]), s = 16n+4q+i
    f32x4 pn0, pn1, pn2;
    {
        const float* e0p = em + (size_t)bidx * Tq;
        f32x4 ea = *(const f32x4*)(e0p + 4 * qidx);
        f32x4 eb = *(const f32x4*)(e0p + 16 + 4 * qidx);
        f32x4 ec = *(const f32x4*)(e0p + 32 + 4 * qidx);
#pragma unroll
        for (int i = 0; i < 4; ++i) {
            pn0[i] = __expf(startT[ 0 + 4 * qidx + i] + ea[i]);
            pn1[i] = __expf(startT[16 + 4 * qidx + i] + eb[i]);
            pn2[i] = __expf(startT[32 + 4 * qidx + i] + ec[i]);
        }
    }

    // loop-invariant LDS addresses (row stride 112B = 56 bf16 states)
    const int wr0 = cidx * 112 + qidx * 8;
    const int wr1 = cidx * 112 + 32 + qidx * 8;
    const int wr2 = cidx * 112 + 64 + qidx * 8;
    const int rd0 = cidx * 112 + 16 * qidx;                      // states 8q..8q+7
    const int rd1 = (qidx == 3) ? 1792 : (cidx * 112 + 64 + 16 * qidx); // 32+8q.. (zeros past 47)
    const f32x4 Zf = {0.f, 0.f, 0.f, 0.f};
    int c2 = 0;

    // initial P^T -> LDS -> B fragments
    *(uint2*)(ldsc + wr0) = make_uint2(cvtpk(pn0[0], pn0[1]), cvtpk(pn0[2], pn0[3]));
    *(uint2*)(ldsc + wr1) = make_uint2(cvtpk(pn1[0], pn1[1]), cvtpk(pn1[2], pn1[3]));
    *(uint2*)(ldsc + wr2) = make_uint2(cvtpk(pn2[0], pn2[1]), cvtpk(pn2[2], pn2[3]));
    __syncthreads();
    s16x8 Bk0 = *(const s16x8*)(ldsc + rd0);
    s16x8 Bk1 = *(const s16x8*)(ldsc + rd1);

    // emission/mask prefetch: 4 named slots, 4 steps of lead
    f32x4 ea_0, eb_0, ec_0, ea_1, eb_1, ec_1;
    f32x4 ea_2, eb_2, ec_2, ea_3, eb_3, ec_3;
    int m_0, m_1, m_2, m_3;
    LOAD_SLOT(0, 1); LOAD_SLOT(1, 2); LOAD_SLOT(2, 3); LOAD_SLOT(3, 4);

    // 128 chunks x 4 steps cover t = 1..512 (t=512 is a masked no-op)
    for (int ch = 0; ch < 128; ++ch) {
        const int tb = 1 + 4 * ch;
        STEP(ea_0, eb_0, ec_0, m_0, 0); LOAD_SLOT(0, tb + 4);
        STEP(ea_1, eb_1, ec_1, m_1, 0); LOAD_SLOT(1, tb + 5);
        STEP(ea_2, eb_2, ec_2, m_2, 0); LOAD_SLOT(2, tb + 6);
        STEP(ea_3, eb_3, ec_3, m_3, 1); LOAD_SLOT(3, tb + 7);
    }

    // z_c = sum_s P[s][c]*exp(end[s]); reduce over the 4 q-groups
    float zacc = 0.f;
#pragma unroll
    for (int i = 0; i < 4; ++i) {
        zacc += pn0[i] * __expf(endT[ 0 + 4 * qidx + i]);
        zacc += pn1[i] * __expf(endT[16 + 4 * qidx + i]);
        zacc += pn2[i] * __expf(endT[32 + 4 * qidx + i]);
    }
    zacc += __shfl_xor(zacc, 16, 64);
    zacc += __shfl_xor(zacc, 32, 64);
    float nl = -(__logf(zacc) + (float)c2 * 0.6931471805599453f);
    nl += __shfl_xor(nl, 1, 64);
    nl += __shfl_xor(nl, 2, 64);
    nl += __shfl_xor(nl, 4, 64);
    nl += __shfl_xor(nl, 8, 64);
    if (j == 0) atomicAdd(out, nl);   // lanes 0..15 held the 16 columns
}

// ---------------- Numerator (gold-path score) ----------------
__global__ __launch_bounds__(256) void crf_llh(
    const float* __restrict__ em, const int* __restrict__ tags,
    const int* __restrict__ mask, const float* __restrict__ startT,
    const float* __restrict__ endT, const float* __restrict__ trans,
    float* __restrict__ out)
{
    float c = 0.0f;
    for (int id = blockIdx.x * blockDim.x + threadIdx.x; id < Lq * Bn;
         id += gridDim.x * blockDim.x) {
        int t  = id >> 10;
        int bb = id & (Bn - 1);
        int tag = tags[id];
        int m_t = mask[id];
        if (t == 0) c += startT[tag];
        bool is_last;
        if (t < Lq - 1) {
            if (m_t) c += em[(size_t)id * Tq + tag];
            int tag1 = tags[id + Bn];
            int m1   = mask[id + Bn];
            if (m1) c += trans[tag * Tq + tag1];
            is_last = (m_t != 0) && (m1 == 0);
        } else {
            is_last = (m_t != 0);
        }
        if (is_last) {
            c += endT[tag];
            int mL = mask[(Lq - 1) * Bn + bb];
            if (mL) c += em[((size_t)(Lq - 1) * Bn + bb) * Tq + tag];
        }
    }
#pragma unroll
    for (int off = 32; off >= 1; off >>= 1)
        c += __shfl_xor(c, off, 64);
    __shared__ float red[4];
    if ((threadIdx.x & 63) == 0) red[threadIdx.x >> 6] = c;
    __syncthreads();
    if (threadIdx.x == 0)
        atomicAdd(out, red[0] + red[1] + red[2] + red[3]);
}

extern "C" void kernel_launch(void* const* d_in, const int* in_sizes, int n_in,
                              void* d_out, int out_size, void* d_ws, size_t ws_size,
                              hipStream_t stream) {
    const float* em     = (const float*)d_in[0];
    const int*   tags   = (const int*)d_in[1];
    const int*   mask   = (const int*)d_in[2];
    const float* startT = (const float*)d_in[3];
    const float* endT   = (const float*)d_in[4];
    const float* trans  = (const float*)d_in[5];
    float* out = (float*)d_out;

    hipMemsetAsync(out, 0, sizeof(float), stream);
    crf_llh<<<512, 256, 0, stream>>>(em, tags, mask, startT, endT, trans, out);
    crf_forward<<<64, 64, 0, stream>>>(em, mask, startT, endT, trans, out);
}

// Round 11
// 137.863 us; speedup vs baseline: 1.2980x; 1.0923x over previous
//
#include <hip/hip_runtime.h>

#define Lq 512
#define Bn 1024
#define Tq 48

typedef float f32x4 __attribute__((ext_vector_type(4)));
typedef short s16x8 __attribute__((ext_vector_type(8)));
typedef unsigned u32x4 __attribute__((ext_vector_type(4)));

#define MFMA(a, b, c) __builtin_amdgcn_mfma_f32_16x16x32_bf16((a), (b), (c), 0, 0, 0)

__device__ __forceinline__ unsigned cvtpk(float lo, float hi) {
    unsigned r;
    asm("v_cvt_pk_bf16_f32 %0, %1, %2" : "=v"(r) : "v"(lo), "v"(hi));
    return r;
}
__device__ __forceinline__ short f2b(float x) {       // fp32 -> bf16 bits, RNE
    unsigned u = __float_as_uint(x);
    return (short)((u + 0x7fffu + ((u >> 16) & 1u)) >> 16);
}

// rebuild B fragments from this lane's own pn: kappa-slot permutation makes
// the C layout feed B directly (no LDS, no cross-lane movement).
// B slot (q,kb0,i): i<4 -> pn0[i] (state 4q+i); i>=4 -> pn1[i-4] (state 12+4q+i)
// B slot (q,kb1,i): i<4 -> pn2[i] (state 32+4q+i); i>=4 -> zero pad
#define PACKB do {                                                            \
    unsigned d0_ = cvtpk(pn0[0], pn0[1]), d1_ = cvtpk(pn0[2], pn0[3]);        \
    unsigned d2_ = cvtpk(pn1[0], pn1[1]), d3_ = cvtpk(pn1[2], pn1[3]);        \
    unsigned d4_ = cvtpk(pn2[0], pn2[1]), d5_ = cvtpk(pn2[2], pn2[3]);        \
    u32x4 b0_ = {d0_, d1_, d2_, d3_};                                         \
    u32x4 b1_ = {d4_, d5_, 0u, 0u};                                           \
    Bk0 = __builtin_bit_cast(s16x8, b0_);                                     \
    Bk1 = __builtin_bit_cast(s16x8, b1_);                                     \
} while (0)

// one forward step: C = W^T*P (6 MFMAs), pn = mask ? C*exp(e) : pn,
// optional IMMEDIATE per-column power-of-2 rescale (R9-proven), repack B.
#define STEP(EA, EB, EC, MV, RS) do {                                         \
    f32x4 C0_ = MFMA(aw00, Bk0, Zf); C0_ = MFMA(aw01, Bk1, C0_);              \
    f32x4 C1_ = MFMA(aw10, Bk0, Zf); C1_ = MFMA(aw11, Bk1, C1_);              \
    f32x4 C2_ = MFMA(aw20, Bk0, Zf); C2_ = MFMA(aw21, Bk1, C2_);              \
    pn0[0] = (MV) ? C0_[0] * __expf((EA)[0]) : pn0[0];                        \
    pn0[1] = (MV) ? C0_[1] * __expf((EA)[1]) : pn0[1];                        \
    pn0[2] = (MV) ? C0_[2] * __expf((EA)[2]) : pn0[2];                        \
    pn0[3] = (MV) ? C0_[3] * __expf((EA)[3]) : pn0[3];                        \
    pn1[0] = (MV) ? C1_[0] * __expf((EB)[0]) : pn1[0];                        \
    pn1[1] = (MV) ? C1_[1] * __expf((EB)[1]) : pn1[1];                        \
    pn1[2] = (MV) ? C1_[2] * __expf((EB)[2]) : pn1[2];                        \
    pn1[3] = (MV) ? C1_[3] * __expf((EB)[3]) : pn1[3];                        \
    pn2[0] = (MV) ? C2_[0] * __expf((EC)[0]) : pn2[0];                        \
    pn2[1] = (MV) ? C2_[1] * __expf((EC)[1]) : pn2[1];                        \
    pn2[2] = (MV) ? C2_[2] * __expf((EC)[2]) : pn2[2];                        \
    pn2[3] = (MV) ? C2_[3] * __expf((EC)[3]) : pn2[3];                        \
    if (RS) {                                                                 \
        float rep_ = __shfl(pn0[0], cidx, 64);      /* column c, state 0 */   \
        int k_ = ((__float_as_int(rep_) >> 23) & 0xff) - 126;                 \
        float scl_ = __int_as_float((127 - k_) << 23);  /* 2^-k exact */      \
        pn0[0]*=scl_; pn0[1]*=scl_; pn0[2]*=scl_; pn0[3]*=scl_;               \
        pn1[0]*=scl_; pn1[1]*=scl_; pn1[2]*=scl_; pn1[3]*=scl_;               \
        pn2[0]*=scl_; pn2[1]*=scl_; pn2[2]*=scl_; pn2[3]*=scl_;               \
        c2 += k_;                                                             \
    }                                                                         \
    PACKB;                                                                    \
} while (0)

// refill slot D with step T's raw emissions (3 x dwordx4) + per-column mask
#define LOAD_SLOT(D, T) do {                                                  \
    int t_ = (T); int v_ = (t_ < Lq); int tc_ = v_ ? t_ : (Lq - 1);           \
    const float* ep_ = em + ((size_t)tc_ * Bn + bidx) * Tq;                   \
    ea_##D = *(const f32x4*)(ep_ + 4 * qidx);                                 \
    eb_##D = *(const f32x4*)(ep_ + 16 + 4 * qidx);                            \
    ec_##D = *(const f32x4*)(ep_ + 32 + 4 * qidx);                            \
    m_##D  = v_ ? mask[tc_ * Bn + bidx] : 0;                                  \
} while (0)

// ---------------- Fused kernel ----------------
// blocks 0..63: MFMA forward algorithm (16 batch columns per wave).
// blocks 64..575: numerator (gold-path score), grid-stride.
__global__ __launch_bounds__(64) void crf_fused(
    const float* __restrict__ em, const int* __restrict__ tags,
    const int* __restrict__ mask, const float* __restrict__ startT,
    const float* __restrict__ endT, const float* __restrict__ trans,
    float* __restrict__ out)
{
    const int j = threadIdx.x;
    __shared__ float shf[Tq * Tq];

    if (blockIdx.x < 64) {
        // ---------------- forward path ----------------
        const int cidx = j & 15;          // batch column within wave
        const int qidx = j >> 4;          // k-slot group
        const int bidx = blockIdx.x * 16 + cidx;

        // stage trans, then build W^T A-fragments under the SAME kappa-slot
        // permutation PACKB uses: kb0,i<4 -> 4q+i ; kb0,i>=4 -> 12+4q+i ;
        // kb1,i<4 -> 32+4q+i ; kb1,i>=4 -> zero pad.
        for (int i = j; i < Tq * Tq; i += 64) shf[i] = trans[i];
        __syncthreads();
        s16x8 aw00, aw01, aw10, aw11, aw20, aw21;
#pragma unroll
        for (int i = 0; i < 8; ++i) {
            int l0 = (i < 4) ? (4 * qidx + i) : (12 + 4 * qidx + i);
            aw00[i] = f2b(__expf(shf[l0 * Tq + cidx]));
            aw10[i] = f2b(__expf(shf[l0 * Tq + 16 + cidx]));
            aw20[i] = f2b(__expf(shf[l0 * Tq + 32 + cidx]));
            if (i < 4) {
                int l1 = 32 + 4 * qidx + i;
                aw01[i] = f2b(__expf(shf[l1 * Tq + cidx]));
                aw11[i] = f2b(__expf(shf[l1 * Tq + 16 + cidx]));
                aw21[i] = f2b(__expf(shf[l1 * Tq + 32 + cidx]));
            } else {
                aw01[i] = 0; aw11[i] = 0; aw21[i] = 0;
            }
        }

        // P_0 (C layout, identity state map): pn_n[i] = exp(start+em0), s=16n+4q+i
        f32x4 pn0, pn1, pn2;
        {
            const float* e0p = em + (size_t)bidx * Tq;
            f32x4 ea = *(const f32x4*)(e0p + 4 * qidx);
            f32x4 eb = *(const f32x4*)(e0p + 16 + 4 * qidx);
            f32x4 ec = *(const f32x4*)(e0p + 32 + 4 * qidx);
#pragma unroll
            for (int i = 0; i < 4; ++i) {
                pn0[i] = __expf(startT[ 0 + 4 * qidx + i] + ea[i]);
                pn1[i] = __expf(startT[16 + 4 * qidx + i] + eb[i]);
                pn2[i] = __expf(startT[32 + 4 * qidx + i] + ec[i]);
            }
        }

        const f32x4 Zf = {0.f, 0.f, 0.f, 0.f};
        s16x8 Bk0, Bk1;
        int c2 = 0;
        PACKB;

        // 4 prefetch slots, named scalars (R9-proven lead of 4 steps)
        f32x4 ea_0, eb_0, ec_0, ea_1, eb_1, ec_1;
        f32x4 ea_2, eb_2, ec_2, ea_3, eb_3, ec_3;
        int m_0, m_1, m_2, m_3;
        LOAD_SLOT(0, 1); LOAD_SLOT(1, 2); LOAD_SLOT(2, 3); LOAD_SLOT(3, 4);

        // 128 chunks x 4 steps cover t = 1..512 (t=512 is a masked no-op);
        // immediate rescale at every 4th step (R9-proven).
        for (int ch = 0; ch < 128; ++ch) {
            const int tb = 1 + 4 * ch;
            STEP(ea_0, eb_0, ec_0, m_0, 0); LOAD_SLOT(0, tb + 4);
            STEP(ea_1, eb_1, ec_1, m_1, 0); LOAD_SLOT(1, tb + 5);
            STEP(ea_2, eb_2, ec_2, m_2, 0); LOAD_SLOT(2, tb + 6);
            STEP(ea_3, eb_3, ec_3, m_3, 1); LOAD_SLOT(3, tb + 7);
        }

        // z_c = sum_s P[s][c]*exp(end[s]); states at this lane: 16n+4q+i
        float zacc = 0.f;
#pragma unroll
        for (int i = 0; i < 4; ++i) {
            zacc += pn0[i] * __expf(endT[ 0 + 4 * qidx + i]);
            zacc += pn1[i] * __expf(endT[16 + 4 * qidx + i]);
            zacc += pn2[i] * __expf(endT[32 + 4 * qidx + i]);
        }
        zacc += __shfl_xor(zacc, 16, 64);
        zacc += __shfl_xor(zacc, 32, 64);
        float nl = -(__logf(zacc) + (float)c2 * 0.6931471805599453f);
        nl += __shfl_xor(nl, 1, 64);
        nl += __shfl_xor(nl, 2, 64);
        nl += __shfl_xor(nl, 4, 64);
        nl += __shfl_xor(nl, 8, 64);
        if (j == 0) atomicAdd(out, nl);
    } else {
        // ---------------- numerator path ----------------
        const int bid = blockIdx.x - 64;          // 0..511
        float c = 0.0f;
        for (int id = bid * 64 + j; id < Lq * Bn; id += 512 * 64) {
            int t  = id >> 10;
            int bb = id & (Bn - 1);
            int tag = tags[id];
            int m_t = mask[id];
            if (t == 0) c += startT[tag];
            bool is_last;
            if (t < Lq - 1) {
                if (m_t) c += em[(size_t)id * Tq + tag];
                int tag1 = tags[id + Bn];
                int m1   = mask[id + Bn];
                if (m1) c += trans[tag * Tq + tag1];
                is_last = (m_t != 0) && (m1 == 0);
            } else {
                is_last = (m_t != 0);
            }
            if (is_last) {
                c += endT[tag];
                int mL = mask[(Lq - 1) * Bn + bb];
                if (mL) c += em[((size_t)(Lq - 1) * Bn + bb) * Tq + tag];
            }
        }
#pragma unroll
        for (int off = 32; off >= 1; off >>= 1)
            c += __shfl_xor(c, off, 64);
        if (j == 0) atomicAdd(out, c);
    }
}

extern "C" void kernel_launch(void* const* d_in, const int* in_sizes, int n_in,
                              void* d_out, int out_size, void* d_ws, size_t ws_size,
                              hipStream_t stream) {
    const float* em     = (const float*)d_in[0];
    const int*   tags   = (const int*)d_in[1];
    const int*   mask   = (const int*)d_in[2];
    const float* startT = (const float*)d_in[3];
    const float* endT   = (const float*)d_in[4];
    const float* trans  = (const float*)d_in[5];
    float* out = (float*)d_out;

    hipMemsetAsync(out, 0, sizeof(float), stream);
    crf_fused<<<576, 64, 0, stream>>>(em, tags, mask, startT, endT, trans, out);
}